// Round 10
// baseline (265.814 us; speedup 1.0000x reference)
//
#include <hip/hip_runtime.h>
#include <math.h>

#define TABLE 256
#define DIM   768
#define NCH   6
#define DCH   128          // DIM / NCH (col head)
#define KTOK  12           // tokens per pass (acc = 24 VGPR as float2)
#define CAP   64           // bucket capacity (P(cnt>64) ~ 0 for Poisson(8))

__device__ __forceinline__ float2 f2zero() { return make_float2(0.f, 0.f); }

// ---------------- kernel 1: zero counts + transpose Wrow ----------------
__global__ __launch_bounds__(256) void k_ztrans(
    const float* __restrict__ Wrow,   // (256, 768)
    float* __restrict__ WrowT,        // (768, 256)
    int* __restrict__ counts)         // (256)
{
    const int d = blockIdx.x;
    const int c = threadIdx.x;
    if (d == 0) counts[c] = 0;
    WrowT[(size_t)d * TABLE + c] = Wrow[(size_t)c * DIM + d];
}

// ---------------- kernel 2: bucket tokens by row id ----------------
__global__ __launch_bounds__(256) void k_bucket(
    const int* __restrict__ tgt, int ntok,
    int* __restrict__ counts, int* __restrict__ bucket)
{
    const int n = blockIdx.x * 256 + threadIdx.x;
    if (n >= ntok) return;
    const int r = tgt[n] >> 8;
    const int pos = atomicAdd(&counts[r], 1);
    if (pos < CAP) bucket[r * CAP + pos] = n;
}

// ---------------- streaming pass: KTOK tokens x 128 cols x NDQ*4 d ----------------
// Single wave. lane = col-pair (float2). tk[] wave-uniform (SGPR-held) -> hv loads
// are uniform (scalar path). Slab reads: 512B contiguous per d row. acc = 24 VGPR.
// No LDS, no barriers, no cross-lane ops.
template<int NDQ>
__device__ __forceinline__ void stream_pass(
    const float* __restrict__ slab,     // (NDQ*4, 256) floats
    const float* __restrict__ hs,       // (ntok, 768)
    const int* tk,                      // KTOK uniform token ids (clamped valid)
    int nvalid,
    int dbase,                          // d offset into hs rows
    int cbase,                          // 0 or 128
    float* __restrict__ outp,           // (ntok, 256) destination
    int lane)
{
    int off[KTOK];
    #pragma unroll
    for (int j = 0; j < KTOK; ++j) off[j] = tk[j] * DIM + dbase;

    float2 acc[KTOK];
    #pragma unroll
    for (int j = 0; j < KTOK; ++j) acc[j] = f2zero();

    const float* sl = slab + cbase + 2 * lane;

    #pragma unroll 2
    for (int dq = 0; dq < NDQ; ++dq) {
        float4 hv[KTOK];                 // uniform loads
        #pragma unroll
        for (int j = 0; j < KTOK; ++j)
            hv[j] = reinterpret_cast<const float4*>(hs + off[j])[dq];
        #pragma unroll
        for (int dd = 0; dd < 4; ++dd) {
            const float2 wv = *reinterpret_cast<const float2*>(
                sl + (size_t)(dq * 4 + dd) * TABLE);
            #pragma unroll
            for (int j = 0; j < KTOK; ++j) {
                const float h = (dd == 0) ? hv[j].x : (dd == 1) ? hv[j].y
                              : (dd == 2) ? hv[j].z : hv[j].w;
                acc[j].x = fmaf(h, wv.x, acc[j].x);
                acc[j].y = fmaf(h, wv.y, acc[j].y);
            }
        }
    }

    #pragma unroll
    for (int j = 0; j < KTOK; ++j)
        if (j < nvalid)
            *reinterpret_cast<float2*>(outp + (size_t)tk[j] * TABLE + cbase + 2 * lane)
                = acc[j];
}

// ---------------- kernel 3: unified streaming GEMMs ----------------
// 256-thread blocks = 4 INDEPENDENT waves (no barriers/LDS). Global wave id:
//   gw in [0, 3072): col head — r = gw&255, rest = gw>>8: chunk = rest>>1,
//                    cbase = (rest&1)*128 — d-chunked partials into col_part.
//   gw in [3072, 3072+2*ntiles): row head — full-DIM pass over L2-resident
//                    WrowT, direct write to row_logits (no partials).
__global__ __launch_bounds__(256) void k_stream(
    const float* __restrict__ hs,
    const float* __restrict__ WrowT,
    const float* __restrict__ CW,
    const int* __restrict__ counts,
    const int* __restrict__ bucket,
    float* __restrict__ row_logits,     // (ntok, 256)
    float* __restrict__ col_part,       // (NCH, ntok, 256)
    int ntok)
{
    const int gw   = blockIdx.x * 4 + (threadIdx.x >> 6);
    const int lane = threadIdx.x & 63;
    const int ncol = 256 * NCH * 2;     // 3072
    const int ntiles = (ntok + KTOK - 1) / KTOK;   // 171
    int tk[KTOK];

    if (gw < ncol) {
        const int r     = gw & 255;
        const int rest  = gw >> 8;      // 0..11
        const int chunk = rest >> 1;    // 0..5
        const int cbase = (rest & 1) * 128;
        const int cnt = min(counts[r], CAP);
        if (cnt == 0) return;
        const float* slab = CW + (size_t)r * DIM * TABLE + (size_t)chunk * DCH * TABLE;
        float* outp = col_part + (size_t)chunk * ntok * TABLE;
        for (int base = 0; base < cnt; base += KTOK) {
            #pragma unroll
            for (int j = 0; j < KTOK; ++j) {
                const int idx = (base + j < cnt) ? (base + j) : base;
                tk[j] = __builtin_amdgcn_readfirstlane(bucket[r * CAP + idx]);
            }
            stream_pass<DCH / 4>(slab, hs, tk, min(KTOK, cnt - base),
                                 chunk * DCH, cbase, outp, lane);
        }
    } else if (gw < ncol + 2 * ntiles) {
        const int t     = gw - ncol;
        const int tile  = t >> 1;
        const int cbase = (t & 1) * 128;
        const int cnt   = min(KTOK, ntok - tile * KTOK);
        #pragma unroll
        for (int j = 0; j < KTOK; ++j) {
            const int idx = (j < cnt) ? j : 0;
            tk[j] = tile * KTOK + idx;
        }
        stream_pass<DIM / 4>(WrowT, hs, tk, cnt, 0, cbase, row_logits, lane);
    }
}

// ---------------- kernel 4: fused partial-sum + bias + NLL ----------------
__device__ __forceinline__ float wave_nll(float4 v, int target, int lane) {
    float m = fmaxf(fmaxf(v.x, v.y), fmaxf(v.z, v.w));
    #pragma unroll
    for (int off = 32; off > 0; off >>= 1) m = fmaxf(m, __shfl_xor(m, off));
    float e = expf(v.x - m) + expf(v.y - m) + expf(v.z - m) + expf(v.w - m);
    float lt = 0.f;
    if (lane == (target >> 2)) {
        const int j = target & 3;
        lt = (j == 0) ? v.x : (j == 1) ? v.y : (j == 2) ? v.z : v.w;
    }
    #pragma unroll
    for (int off = 32; off > 0; off >>= 1) {
        e  += __shfl_xor(e, off);
        lt += __shfl_xor(lt, off);
    }
    return m + logf(e) - lt;
}

__global__ __launch_bounds__(256) void k_nll2(
    const float* __restrict__ row_logits,
    const float* __restrict__ col_part,
    const float* __restrict__ brow,
    const float* __restrict__ cbias,
    const int* __restrict__ tgt, int ntok,
    float* __restrict__ per_tok)
{
    const int n = blockIdx.x * 4 + (threadIdx.x >> 6);
    if (n >= ntok) return;
    const int lane = threadIdx.x & 63;
    const int t = tgt[n];
    const int r = t >> 8;

    float4 rl = reinterpret_cast<const float4*>(brow)[lane];
    {
        const float4 a = reinterpret_cast<const float4*>(
            row_logits + (size_t)n * TABLE)[lane];
        rl.x += a.x; rl.y += a.y; rl.z += a.z; rl.w += a.w;
    }
    float4 cl = reinterpret_cast<const float4*>(cbias + (size_t)r * TABLE)[lane];
    #pragma unroll
    for (int ch = 0; ch < NCH; ++ch) {
        const float4 b = reinterpret_cast<const float4*>(
            col_part + ((size_t)ch * ntok + n) * TABLE)[lane];
        cl.x += b.x; cl.y += b.y; cl.z += b.z; cl.w += b.w;
    }
    const float lr = wave_nll(rl, r, lane);
    const float lc = wave_nll(cl, t & 255, lane);
    if (lane == 0) per_tok[n] = lr + lc;
}

// ---------------- kernel 5: mean reduce ----------------
__global__ __launch_bounds__(256) void k_reduce(
    const float* __restrict__ per_tok, int ntok, float* __restrict__ out)
{
    __shared__ float red[256];
    const int c = threadIdx.x;
    float s = 0.f;
    for (int i = c; i < ntok; i += 256) s += per_tok[i];
    red[c] = s;
    __syncthreads();
    #pragma unroll
    for (int k = 128; k > 0; k >>= 1) {
        if (c < k) red[c] += red[c + k];
        __syncthreads();
    }
    if (c == 0) out[0] = red[0] / (float)ntok;
}

extern "C" void kernel_launch(void* const* d_in, const int* in_sizes, int n_in,
                              void* d_out, int out_size, void* d_ws, size_t ws_size,
                              hipStream_t stream) {
    const float* hs    = (const float*)d_in[0];
    const int*   tgt   = (const int*)d_in[1];
    const float* Wrow  = (const float*)d_in[2];
    const float* brow  = (const float*)d_in[3];
    const float* CW    = (const float*)d_in[4];
    const float* cbias = (const float*)d_in[5];
    float* out = (float*)d_out;

    const int ntok = in_sizes[1];   // 2048

    // workspace layout (bytes) — ~16 MB total
    char* ws = (char*)d_ws;
    int*   counts     = (int*)(ws);                                // 1 KB
    int*   bucket     = (int*)(ws + 1024);                         // 64 KB
    float* WrowT      = (float*)(ws + 1024 + 256 * CAP * 4);       // 768 KB
    char*  p0         = (char*)WrowT + (size_t)DIM * TABLE * 4;
    float* row_logits = (float*)p0;                                // 2 MB
    float* col_part   = row_logits + (size_t)ntok * TABLE;         // 12.6 MB
    float* per_tok    = col_part + (size_t)NCH * ntok * TABLE;     // 8 KB

    const int ntiles = (ntok + KTOK - 1) / KTOK;          // 171
    const int nwaves = 256 * NCH * 2 + 2 * ntiles;        // 3072 + 342 = 3414
    const int nblk   = (nwaves + 3) / 4;                  // 854

    k_ztrans <<<DIM, 256, 0, stream>>>(Wrow, WrowT, counts);
    k_bucket <<<(ntok + 255) / 256, 256, 0, stream>>>(tgt, ntok, counts, bucket);
    k_stream <<<nblk, 256, 0, stream>>>(hs, WrowT, CW, counts, bucket,
                                        row_logits, col_part, ntok);
    k_nll2   <<<(ntok + 3) / 4, 256, 0, stream>>>(row_logits, col_part, brow, cbias,
                                                  tgt, ntok, per_tok);
    k_reduce <<<1, 256, 0, stream>>>(per_tok, ntok, out);
}

// Round 12
// 125.961 us; speedup vs baseline: 2.1103x; 2.1103x over previous
//
#include <hip/hip_runtime.h>
#include <math.h>

#define TABLE 256
#define DIM   768
#define NCH   6
#define DCH   128          // DIM / NCH
#define KTOK  12           // tokens per pass (acc = 24 VGPR as float2)
#define CAP   64           // bucket capacity (P(cnt>64) ~ 0 for Poisson(8))

__device__ __forceinline__ float2 f2zero() { return make_float2(0.f, 0.f); }

// ---------------- kernel 1: zero counts + transpose Wrow ----------------
__global__ __launch_bounds__(256) void k_ztrans(
    const float* __restrict__ Wrow,   // (256, 768)
    float* __restrict__ WrowT,        // (768, 256)
    int* __restrict__ counts)         // (256)
{
    const int d = blockIdx.x;
    const int c = threadIdx.x;
    if (d == 0) counts[c] = 0;
    WrowT[(size_t)d * TABLE + c] = Wrow[(size_t)c * DIM + d];
}

// ---------------- kernel 2: bucket tokens by row id ----------------
__global__ __launch_bounds__(256) void k_bucket(
    const int* __restrict__ tgt, int ntok,
    int* __restrict__ counts, int* __restrict__ bucket)
{
    const int n = blockIdx.x * 256 + threadIdx.x;
    if (n >= ntok) return;
    const int r = tgt[n] >> 8;
    const int pos = atomicAdd(&counts[r], 1);
    if (pos < CAP) bucket[r * CAP + pos] = n;
}

// ---------------- one streaming pass: 12 tokens x 128 cols x DCH d ----------------
// Single wave, half the columns (cbase = 0 or 128). lane = col-pair (float2).
// tk[] wave-uniform. Slab reads: 512B contiguous per d. acc[12] float2 = 24 VGPR.
// No LDS, no barriers, reduction-free (each lane owns its 2 cols end-to-end).
__device__ __forceinline__ void stream_pass(
    const float* __restrict__ slab,     // chunk base: (DCH, 256) floats
    const float* __restrict__ hs,       // (ntok, 768)
    const int* tk,                      // KTOK uniform token ids (clamped valid)
    int nvalid,
    int dbase,                          // chunk * DCH
    int cbase,                          // 0 or 128
    float* __restrict__ outp,           // partial base (ntok, 256)
    int lane)
{
    int off[KTOK];
    #pragma unroll
    for (int j = 0; j < KTOK; ++j) off[j] = tk[j] * DIM + dbase;

    float2 acc[KTOK];
    #pragma unroll
    for (int j = 0; j < KTOK; ++j) acc[j] = f2zero();

    const float* sl = slab + cbase + 2 * lane;

    #pragma unroll 2
    for (int dq = 0; dq < DCH / 4; ++dq) {
        float4 hv[KTOK];                 // uniform loads
        #pragma unroll
        for (int j = 0; j < KTOK; ++j)
            hv[j] = reinterpret_cast<const float4*>(hs + off[j])[dq];
        #pragma unroll
        for (int dd = 0; dd < 4; ++dd) {
            const float2 wv = *reinterpret_cast<const float2*>(
                sl + (size_t)(dq * 4 + dd) * TABLE);
            #pragma unroll
            for (int j = 0; j < KTOK; ++j) {
                const float h = (dd == 0) ? hv[j].x : (dd == 1) ? hv[j].y
                              : (dd == 2) ? hv[j].z : hv[j].w;
                acc[j].x = fmaf(h, wv.x, acc[j].x);
                acc[j].y = fmaf(h, wv.y, acc[j].y);
            }
        }
    }

    #pragma unroll
    for (int j = 0; j < KTOK; ++j)
        if (j < nvalid)
            *reinterpret_cast<float2*>(outp + (size_t)tk[j] * TABLE + cbase + 2 * lane)
                = acc[j];
}

// ---------------- kernel 3: streaming partial GEMMs ----------------
// 128-thread blocks = 2 INDEPENDENT waves (no barriers/LDS). Global wave id:
//   gw in [0, 3072): col head — r = gw&255, rest = gw>>8: chunk = rest>>1,
//                    cbase = (rest&1)*128
//   gw in [3072, 3072+2052): row head — b = gw-3072, tile = b%ntiles,
//                    rest = b/ntiles: chunk = rest>>1, cbase = (rest&1)*128
__global__ __launch_bounds__(128) void k_stream(
    const float* __restrict__ hs,
    const float* __restrict__ WrowT,
    const float* __restrict__ CW,
    const int* __restrict__ counts,
    const int* __restrict__ bucket,
    float* __restrict__ row_part,       // (NCH, ntok, 256)
    float* __restrict__ col_part,       // (NCH, ntok, 256)
    int ntok)
{
    const int gw   = blockIdx.x * 2 + (threadIdx.x >> 6);
    const int lane = threadIdx.x & 63;
    const int ncol = 256 * NCH * 2;     // 3072
    int tk[KTOK];

    if (gw < ncol) {
        const int r     = gw & 255;
        const int rest  = gw >> 8;      // 0..11
        const int chunk = rest >> 1;    // 0..5
        const int cbase = (rest & 1) * 128;
        const int cnt = min(counts[r], CAP);
        if (cnt == 0) return;
        const float* slab = CW + (size_t)r * DIM * TABLE + (size_t)chunk * DCH * TABLE;
        float* outp = col_part + (size_t)chunk * ntok * TABLE;
        for (int base = 0; base < cnt; base += KTOK) {
            #pragma unroll
            for (int j = 0; j < KTOK; ++j) {
                const int idx = (base + j < cnt) ? (base + j) : base;
                tk[j] = __builtin_amdgcn_readfirstlane(bucket[r * CAP + idx]);
            }
            stream_pass(slab, hs, tk, min(KTOK, cnt - base),
                        chunk * DCH, cbase, outp, lane);
        }
    } else {
        const int b      = gw - ncol;
        const int ntiles = (ntok + KTOK - 1) / KTOK;   // 171
        if (b >= ntiles * NCH * 2) return;
        const int tile   = b % ntiles;
        const int rest   = b / ntiles;  // 0..11
        const int chunk  = rest >> 1;
        const int cbase  = (rest & 1) * 128;
        const int cnt    = min(KTOK, ntok - tile * KTOK);
        #pragma unroll
        for (int j = 0; j < KTOK; ++j) {
            const int idx = (j < cnt) ? j : 0;
            tk[j] = tile * KTOK + idx;
        }
        const float* slab = WrowT + (size_t)chunk * DCH * TABLE;
        float* outp = row_part + (size_t)chunk * ntok * TABLE;
        stream_pass(slab, hs, tk, cnt, chunk * DCH, cbase, outp, lane);
    }
}

// ---------------- kernel 4: fused partial-sum + bias + NLL ----------------
__device__ __forceinline__ float wave_nll(float4 v, int target, int lane) {
    float m = fmaxf(fmaxf(v.x, v.y), fmaxf(v.z, v.w));
    #pragma unroll
    for (int off = 32; off > 0; off >>= 1) m = fmaxf(m, __shfl_xor(m, off));
    float e = expf(v.x - m) + expf(v.y - m) + expf(v.z - m) + expf(v.w - m);
    float lt = 0.f;
    if (lane == (target >> 2)) {
        const int j = target & 3;
        lt = (j == 0) ? v.x : (j == 1) ? v.y : (j == 2) ? v.z : v.w;
    }
    #pragma unroll
    for (int off = 32; off > 0; off >>= 1) {
        e  += __shfl_xor(e, off);
        lt += __shfl_xor(lt, off);
    }
    return m + logf(e) - lt;
}

__global__ __launch_bounds__(256) void k_nll2(
    const float* __restrict__ row_part,
    const float* __restrict__ col_part,
    const float* __restrict__ brow,
    const float* __restrict__ cbias,
    const int* __restrict__ tgt, int ntok,
    float* __restrict__ per_tok)
{
    const int n = blockIdx.x * 4 + (threadIdx.x >> 6);
    if (n >= ntok) return;
    const int lane = threadIdx.x & 63;
    const int t = tgt[n];
    const int r = t >> 8;

    float4 rl = reinterpret_cast<const float4*>(brow)[lane];
    float4 cl = reinterpret_cast<const float4*>(cbias + (size_t)r * TABLE)[lane];
    #pragma unroll
    for (int ch = 0; ch < NCH; ++ch) {
        const float4 a = reinterpret_cast<const float4*>(
            row_part + ((size_t)ch * ntok + n) * TABLE)[lane];
        const float4 b = reinterpret_cast<const float4*>(
            col_part + ((size_t)ch * ntok + n) * TABLE)[lane];
        rl.x += a.x; rl.y += a.y; rl.z += a.z; rl.w += a.w;
        cl.x += b.x; cl.y += b.y; cl.z += b.z; cl.w += b.w;
    }
    const float lr = wave_nll(rl, r, lane);
    const float lc = wave_nll(cl, t & 255, lane);
    if (lane == 0) per_tok[n] = lr + lc;
}

// ---------------- kernel 5: mean reduce ----------------
__global__ __launch_bounds__(256) void k_reduce(
    const float* __restrict__ per_tok, int ntok, float* __restrict__ out)
{
    __shared__ float red[256];
    const int c = threadIdx.x;
    float s = 0.f;
    for (int i = c; i < ntok; i += 256) s += per_tok[i];
    red[c] = s;
    __syncthreads();
    #pragma unroll
    for (int k = 128; k > 0; k >>= 1) {
        if (c < k) red[c] += red[c + k];
        __syncthreads();
    }
    if (c == 0) out[0] = red[0] / (float)ntok;
}

extern "C" void kernel_launch(void* const* d_in, const int* in_sizes, int n_in,
                              void* d_out, int out_size, void* d_ws, size_t ws_size,
                              hipStream_t stream) {
    const float* hs    = (const float*)d_in[0];
    const int*   tgt   = (const int*)d_in[1];
    const float* Wrow  = (const float*)d_in[2];
    const float* brow  = (const float*)d_in[3];
    const float* CW    = (const float*)d_in[4];
    const float* cbias = (const float*)d_in[5];
    float* out = (float*)d_out;

    const int ntok = in_sizes[1];   // 2048

    // workspace layout (bytes) — ~26.2 MB total
    char* ws = (char*)d_ws;
    int*   counts   = (int*)(ws);                                  // 1 KB
    int*   bucket   = (int*)(ws + 1024);                           // 64 KB
    float* WrowT    = (float*)(ws + 1024 + 256 * CAP * 4);         // 768 KB
    char*  p0       = (char*)WrowT + (size_t)DIM * TABLE * 4;
    float* row_part = (float*)p0;                                  // 12.6 MB
    float* col_part = row_part + (size_t)NCH * ntok * TABLE;       // 12.6 MB
    float* per_tok  = col_part + (size_t)NCH * ntok * TABLE;       // 8 KB

    const int ntiles = (ntok + KTOK - 1) / KTOK;          // 171
    const int nwaves = 256 * NCH * 2 + ntiles * NCH * 2;  // 3072 + 2052 = 5124
    const int nblk   = (nwaves + 1) / 2;                  // 2562

    k_ztrans <<<DIM, 256, 0, stream>>>(Wrow, WrowT, counts);
    k_bucket <<<(ntok + 255) / 256, 256, 0, stream>>>(tgt, ntok, counts, bucket);
    k_stream <<<nblk, 128, 0, stream>>>(hs, WrowT, CW, counts, bucket,
                                        row_part, col_part, ntok);
    k_nll2   <<<(ntok + 3) / 4, 256, 0, stream>>>(row_part, col_part, brow, cbias,
                                                  tgt, ntok, per_tok);
    k_reduce <<<1, 256, 0, stream>>>(per_tok, ntok, out);
}

// Round 13
// 71.818 us; speedup vs baseline: 3.7012x; 1.7539x over previous
//
#include <hip/hip_runtime.h>
#include <math.h>

#define TABLE 256
#define DIM   768
#define NCH   6
#define DCH   128          // DIM / NCH
#define KTOK  12           // tokens per pass
#define CAP   64           // bucket capacity (P(cnt>64) ~ 0 for Poisson(8))

__device__ __forceinline__ float2 f2zero() { return make_float2(0.f, 0.f); }

// ---------------- kernel 1: zero counts + transpose Wrow ----------------
__global__ __launch_bounds__(256) void k_ztrans(
    const float* __restrict__ Wrow,   // (256, 768)
    float* __restrict__ WrowT,        // (768, 256)
    int* __restrict__ counts)         // (256)
{
    const int d = blockIdx.x;
    const int c = threadIdx.x;
    if (d == 0) counts[c] = 0;
    WrowT[(size_t)d * TABLE + c] = Wrow[(size_t)c * DIM + d];
}

// ---------------- kernel 2: bucket tokens by row id ----------------
__global__ __launch_bounds__(256) void k_bucket(
    const int* __restrict__ tgt, int ntok,
    int* __restrict__ counts, int* __restrict__ bucket)
{
    const int n = blockIdx.x * 256 + threadIdx.x;
    if (n >= ntok) return;
    const int r = tgt[n] >> 8;
    const int pos = atomicAdd(&counts[r], 1);
    if (pos < CAP) bucket[r * CAP + pos] = n;
}

// ---------------- one streaming pass: 12 tokens x 128 cols x DCH d ----------------
// Single wave per block. Stage the 12 token h-chunks into LDS (coalesced float4,
// 2 tokens per instr), then the inner loop reads h via uniform-address
// ds_read_b128 broadcasts (short-latency, conflict-free) — the only VMEM in the
// hot loop is the 4 address-independent slab loads per dq, which pipeline.
__device__ __forceinline__ void stream_pass(
    const float* __restrict__ slab,     // chunk base: (DCH, 256) floats
    const float* __restrict__ hs,       // (ntok, 768)
    const int* tk,                      // KTOK uniform token ids (clamped valid)
    int nvalid,
    int dbase,                          // chunk * DCH
    int cbase,                          // 0 or 128
    float4 (*hs_lds)[DCH / 4],          // LDS [KTOK][32] float4 (6 KB)
    float* __restrict__ outp,           // partial base (ntok, 256)
    int lane)
{
    // ---- stage: 2 tokens per iteration, full wave, coalesced ----
    const int half = lane >> 5;         // 0/1 -> which of the token pair
    const int q    = lane & 31;         // quad within the 128-float chunk
    __syncthreads();                    // 1-wave block: trivial; guards WAR on hs_lds
    #pragma unroll
    for (int i = 0; i < KTOK / 2; ++i) {
        const int tt = (half == 0) ? tk[2 * i] : tk[2 * i + 1];
        const float4 v = *reinterpret_cast<const float4*>(
            hs + (size_t)tt * DIM + dbase + 4 * q);
        hs_lds[2 * i + half][q] = v;
    }
    __syncthreads();                    // RAW: staging -> broadcast reads

    float2 acc[KTOK];
    #pragma unroll
    for (int j = 0; j < KTOK; ++j) acc[j] = f2zero();

    const float* sl = slab + cbase + 2 * lane;

    #pragma unroll 2
    for (int dq = 0; dq < DCH / 4; ++dq) {
        float4 hv[KTOK];                 // uniform LDS broadcasts
        #pragma unroll
        for (int j = 0; j < KTOK; ++j) hv[j] = hs_lds[j][dq];
        #pragma unroll
        for (int dd = 0; dd < 4; ++dd) {
            const float2 wv = *reinterpret_cast<const float2*>(
                sl + (size_t)(dq * 4 + dd) * TABLE);
            #pragma unroll
            for (int j = 0; j < KTOK; ++j) {
                const float h = (dd == 0) ? hv[j].x : (dd == 1) ? hv[j].y
                              : (dd == 2) ? hv[j].z : hv[j].w;
                acc[j].x = fmaf(h, wv.x, acc[j].x);
                acc[j].y = fmaf(h, wv.y, acc[j].y);
            }
        }
    }

    #pragma unroll
    for (int j = 0; j < KTOK; ++j)
        if (j < nvalid)
            *reinterpret_cast<float2*>(outp + (size_t)tk[j] * TABLE + cbase + 2 * lane)
                = acc[j];
}

// ---------------- kernel 3: streaming partial GEMMs ----------------
// 64-thread blocks = 1 wave. Block id:
//   bid in [0, 3072): col head — r = bid&255, rest = bid>>8: chunk = rest>>1,
//                     cbase = (rest&1)*128
//   bid in [3072, 3072+2052): row head — b = bid-3072, tile = b%ntiles,
//                     rest = b/ntiles: chunk = rest>>1, cbase = (rest&1)*128
__global__ __launch_bounds__(64) void k_stream(
    const float* __restrict__ hs,
    const float* __restrict__ WrowT,
    const float* __restrict__ CW,
    const int* __restrict__ counts,
    const int* __restrict__ bucket,
    float* __restrict__ row_part,       // (NCH, ntok, 256)
    float* __restrict__ col_part,       // (NCH, ntok, 256)
    int ntok)
{
    __shared__ float4 hs_lds[KTOK][DCH / 4];   // 6 KB

    const int bid  = blockIdx.x;
    const int lane = threadIdx.x;
    const int ncol = 256 * NCH * 2;     // 3072
    int tk[KTOK];

    if (bid < ncol) {
        const int r     = bid & 255;
        const int rest  = bid >> 8;     // 0..11
        const int chunk = rest >> 1;    // 0..5
        const int cbase = (rest & 1) * 128;
        const int cnt = min(counts[r], CAP);
        if (cnt == 0) return;
        const float* slab = CW + (size_t)r * DIM * TABLE + (size_t)chunk * DCH * TABLE;
        float* outp = col_part + (size_t)chunk * ntok * TABLE;
        for (int base = 0; base < cnt; base += KTOK) {
            #pragma unroll
            for (int j = 0; j < KTOK; ++j) {
                const int idx = (base + j < cnt) ? (base + j) : base;
                tk[j] = __builtin_amdgcn_readfirstlane(bucket[r * CAP + idx]);
            }
            stream_pass(slab, hs, tk, min(KTOK, cnt - base),
                        chunk * DCH, cbase, hs_lds, outp, lane);
        }
    } else {
        const int b      = bid - ncol;
        const int ntiles = (ntok + KTOK - 1) / KTOK;   // 171
        if (b >= ntiles * NCH * 2) return;
        const int tile   = b % ntiles;
        const int rest   = b / ntiles;  // 0..11
        const int chunk  = rest >> 1;
        const int cbase  = (rest & 1) * 128;
        const int cnt    = min(KTOK, ntok - tile * KTOK);
        #pragma unroll
        for (int j = 0; j < KTOK; ++j) {
            const int idx = (j < cnt) ? j : 0;
            tk[j] = tile * KTOK + idx;
        }
        const float* slab = WrowT + (size_t)chunk * DCH * TABLE;
        float* outp = row_part + (size_t)chunk * ntok * TABLE;
        stream_pass(slab, hs, tk, cnt, chunk * DCH, cbase, hs_lds, outp, lane);
    }
}

// ---------------- kernel 4: fused partial-sum + bias + NLL ----------------
__device__ __forceinline__ float wave_nll(float4 v, int target, int lane) {
    float m = fmaxf(fmaxf(v.x, v.y), fmaxf(v.z, v.w));
    #pragma unroll
    for (int off = 32; off > 0; off >>= 1) m = fmaxf(m, __shfl_xor(m, off));
    float e = expf(v.x - m) + expf(v.y - m) + expf(v.z - m) + expf(v.w - m);
    float lt = 0.f;
    if (lane == (target >> 2)) {
        const int j = target & 3;
        lt = (j == 0) ? v.x : (j == 1) ? v.y : (j == 2) ? v.z : v.w;
    }
    #pragma unroll
    for (int off = 32; off > 0; off >>= 1) {
        e  += __shfl_xor(e, off);
        lt += __shfl_xor(lt, off);
    }
    return m + logf(e) - lt;
}

__global__ __launch_bounds__(256) void k_nll2(
    const float* __restrict__ row_part,
    const float* __restrict__ col_part,
    const float* __restrict__ brow,
    const float* __restrict__ cbias,
    const int* __restrict__ tgt, int ntok,
    float* __restrict__ per_tok)
{
    const int n = blockIdx.x * 4 + (threadIdx.x >> 6);
    if (n >= ntok) return;
    const int lane = threadIdx.x & 63;
    const int t = tgt[n];
    const int r = t >> 8;

    float4 rl = reinterpret_cast<const float4*>(brow)[lane];
    float4 cl = reinterpret_cast<const float4*>(cbias + (size_t)r * TABLE)[lane];
    #pragma unroll
    for (int ch = 0; ch < NCH; ++ch) {
        const float4 a = reinterpret_cast<const float4*>(
            row_part + ((size_t)ch * ntok + n) * TABLE)[lane];
        const float4 b = reinterpret_cast<const float4*>(
            col_part + ((size_t)ch * ntok + n) * TABLE)[lane];
        rl.x += a.x; rl.y += a.y; rl.z += a.z; rl.w += a.w;
        cl.x += b.x; cl.y += b.y; cl.z += b.z; cl.w += b.w;
    }
    const float lr = wave_nll(rl, r, lane);
    const float lc = wave_nll(cl, t & 255, lane);
    if (lane == 0) per_tok[n] = lr + lc;
}

// ---------------- kernel 5: mean reduce ----------------
__global__ __launch_bounds__(256) void k_reduce(
    const float* __restrict__ per_tok, int ntok, float* __restrict__ out)
{
    __shared__ float red[256];
    const int c = threadIdx.x;
    float s = 0.f;
    for (int i = c; i < ntok; i += 256) s += per_tok[i];
    red[c] = s;
    __syncthreads();
    #pragma unroll
    for (int k = 128; k > 0; k >>= 1) {
        if (c < k) red[c] += red[c + k];
        __syncthreads();
    }
    if (c == 0) out[0] = red[0] / (float)ntok;
}

extern "C" void kernel_launch(void* const* d_in, const int* in_sizes, int n_in,
                              void* d_out, int out_size, void* d_ws, size_t ws_size,
                              hipStream_t stream) {
    const float* hs    = (const float*)d_in[0];
    const int*   tgt   = (const int*)d_in[1];
    const float* Wrow  = (const float*)d_in[2];
    const float* brow  = (const float*)d_in[3];
    const float* CW    = (const float*)d_in[4];
    const float* cbias = (const float*)d_in[5];
    float* out = (float*)d_out;

    const int ntok = in_sizes[1];   // 2048

    // workspace layout (bytes) — ~26.2 MB total
    char* ws = (char*)d_ws;
    int*   counts   = (int*)(ws);                                  // 1 KB
    int*   bucket   = (int*)(ws + 1024);                           // 64 KB
    float* WrowT    = (float*)(ws + 1024 + 256 * CAP * 4);         // 768 KB
    char*  p0       = (char*)WrowT + (size_t)DIM * TABLE * 4;
    float* row_part = (float*)p0;                                  // 12.6 MB
    float* col_part = row_part + (size_t)NCH * ntok * TABLE;       // 12.6 MB
    float* per_tok  = col_part + (size_t)NCH * ntok * TABLE;       // 8 KB

    const int ntiles = (ntok + KTOK - 1) / KTOK;          // 171
    const int nblk   = 256 * NCH * 2 + ntiles * NCH * 2;  // 3072 + 2052 = 5124

    k_ztrans <<<DIM, 256, 0, stream>>>(Wrow, WrowT, counts);
    k_bucket <<<(ntok + 255) / 256, 256, 0, stream>>>(tgt, ntok, counts, bucket);
    k_stream <<<nblk, 64, 0, stream>>>(hs, WrowT, CW, counts, bucket,
                                       row_part, col_part, ntok);
    k_nll2   <<<(ntok + 3) / 4, 256, 0, stream>>>(row_part, col_part, brow, cbias,
                                                  tgt, ntok, per_tok);
    k_reduce <<<1, 256, 0, stream>>>(per_tok, ntok, out);
}